// Round 4
// baseline (940.970 us; speedup 1.0000x reference)
//
#include <hip/hip_runtime.h>
#include <hip/hip_bf16.h>
#include <stdint.h>

#define BATCH 8192
#define IN_F  4096
#define OUT_F 4096
#define NFRAG 32
#define FSIZE 128
#define COMP  512

typedef float f32x4 __attribute__((ext_vector_type(4)));
typedef short bf16x8 __attribute__((ext_vector_type(8)));

__device__ __forceinline__ unsigned short f2bf(float f) {
  union { float f; unsigned u; } v; v.f = f;
  return (unsigned short)((v.u + 0x7FFFu + ((v.u >> 16) & 1u)) >> 16);
}
__device__ __forceinline__ unsigned pack2(float a, float b) {
  return (unsigned)f2bf(a) | ((unsigned)f2bf(b) << 16);
}

typedef const __attribute__((address_space(1))) unsigned* as1_u32p;
typedef __attribute__((address_space(3))) unsigned* as3_u32p;

// async global->LDS, 16B per lane. LDS dest must be wave-uniform base + lane*16,
// which our chunk mapping (c = i*256 + wave*64 + lane) satisfies.
__device__ __forceinline__ void lds_load16(const void* g, void* l) {
  __builtin_amdgcn_global_load_lds((as1_u32p)(uintptr_t)g, (as3_u32p)(uintptr_t)l, 16, 0, 0);
}

// ---------------- routing: probs + scaled bf16 copies ----------------
// one block (256 thr) per row; thread t owns elems [16t,16t+16) == fragment t>>3
__global__ __launch_bounds__(256) void k_route(
    const float* __restrict__ x, const float* __restrict__ sel,
    unsigned short* __restrict__ xw, unsigned short* __restrict__ xm) {
  __shared__ float red[256];
  __shared__ float sc[NFRAG];
  const int b = blockIdx.x;
  const int t = threadIdx.x;
  const float* xr = x + (size_t)b * IN_F;
  const int frag = t >> 3;

  float4 v0 = *(const float4*)&xr[t * 16 + 0];
  float4 v1 = *(const float4*)&xr[t * 16 + 4];
  float4 v2 = *(const float4*)&xr[t * 16 + 8];
  float4 v3 = *(const float4*)&xr[t * 16 + 12];
  const float* sw = sel + frag * FSIZE + (t & 7) * 16;
  float4 s0 = *(const float4*)&sw[0];
  float4 s1 = *(const float4*)&sw[4];
  float4 s2 = *(const float4*)&sw[8];
  float4 s3 = *(const float4*)&sw[12];
  float d = v0.x*s0.x + v0.y*s0.y + v0.z*s0.z + v0.w*s0.w
          + v1.x*s1.x + v1.y*s1.y + v1.z*s1.z + v1.w*s1.w
          + v2.x*s2.x + v2.y*s2.y + v2.z*s2.z + v2.w*s2.w
          + v3.x*s3.x + v3.y*s3.y + v3.z*s3.z + v3.w*s3.w;
  red[t] = d;
  __syncthreads();
  if (t < NFRAG) {
    float s = 0.f;
#pragma unroll
    for (int j = 0; j < 8; ++j) s += red[t * 8 + j];
    sc[t] = s;
  }
  __syncthreads();
  // redundant per-thread softmax over 32 scores (cheap)
  float mx = sc[0];
#pragma unroll
  for (int f = 1; f < NFRAG; ++f) mx = fmaxf(mx, sc[f]);
  float den = 0.f;
#pragma unroll
  for (int f = 0; f < NFRAG; ++f) den += __expf(sc[f] - mx);
  const float p = __expf(sc[frag] - mx) / den;
  const float q = 1.f - p;

  const size_t base = (size_t)b * IN_F + (size_t)t * 16;
  uint4 w;
  w.x = pack2(v0.x*p, v0.y*p); w.y = pack2(v0.z*p, v0.w*p);
  w.z = pack2(v1.x*p, v1.y*p); w.w = pack2(v1.z*p, v1.w*p);
  *(uint4*)&xw[base] = w;
  w.x = pack2(v2.x*p, v2.y*p); w.y = pack2(v2.z*p, v2.w*p);
  w.z = pack2(v3.x*p, v3.y*p); w.w = pack2(v3.z*p, v3.w*p);
  *(uint4*)&xw[base + 8] = w;
  w.x = pack2(v0.x*q, v0.y*q); w.y = pack2(v0.z*q, v0.w*q);
  w.z = pack2(v1.x*q, v1.y*q); w.w = pack2(v1.z*q, v1.w*q);
  *(uint4*)&xm[base] = w;
  w.x = pack2(v2.x*q, v2.y*q); w.y = pack2(v2.z*q, v2.w*q);
  w.z = pack2(v3.x*q, v3.y*q); w.w = pack2(v3.z*q, v3.w*q);
  *(uint4*)&xm[base + 8] = w;
}

// ---------------- f32 [R][C] -> bf16 [C][R] tiled transpose-convert ----------------
__global__ __launch_bounds__(256) void k_transpose_bf16(
    const float* __restrict__ src, unsigned short* __restrict__ dst, int R, int C) {
  __shared__ float tile[64][65];
  const int t = threadIdx.x;
  const int c0 = blockIdx.x * 64, r0 = blockIdx.y * 64;
#pragma unroll
  for (int i = 0; i < 4; ++i) {
    const int q = i * 256 + t;
    const int row = q >> 4;
    const int col = (q & 15) << 2;
    float4 v = *(const float4*)&src[(size_t)(r0 + row) * C + c0 + col];
    tile[row][col + 0] = v.x; tile[row][col + 1] = v.y;
    tile[row][col + 2] = v.z; tile[row][col + 3] = v.w;
  }
  __syncthreads();
#pragma unroll
  for (int i = 0; i < 4; ++i) {
    const int q = i * 256 + t;
    const int orow = q >> 4;        // dst row (= src col)
    const int oc = (q & 15) << 2;   // dst col (= src row)
    ushort4 o;
    o.x = f2bf(tile[oc + 0][orow]);
    o.y = f2bf(tile[oc + 1][orow]);
    o.z = f2bf(tile[oc + 2][orow]);
    o.w = f2bf(tile[oc + 3][orow]);
    *(ushort4*)&dst[(size_t)(c0 + orow) * R + r0 + oc] = o;
  }
}

// ---------------- bf16 GEMM, B^T input (m97 structure) ----------------
// C[M][N] = A[M][K] @ Bt[N][K]^T.  EPI: 0 = store f32, 1 = C += (f32), 2 = store bf16.
#define BM 128
#define BN 128
#define BK 64

template <int EPI>
__global__ __launch_bounds__(256) void k_gemm_bt(
    const unsigned short* __restrict__ A, const unsigned short* __restrict__ Bt,
    void* __restrict__ Cp, int M, int N, int K) {
  __shared__ unsigned short lA[BM * BK];
  __shared__ unsigned short lB[BN * BK];
  const int t = threadIdx.x;
  const int lane = t & 63;
  const int wave = t >> 6;
  const int wr = wave >> 1, wc = wave & 1;      // 2x2 waves of 64x64
  const int hi = lane >> 4, lo = lane & 15;
  const int bm = blockIdx.y * BM, bn = blockIdx.x * BN;

  f32x4 acc[4][4] = {};

  for (int kt = 0; kt < K; kt += BK) {
    // stage A and Bt tiles: 1024 chunks of 16B each, 4 issues/thread/tile
#pragma unroll
    for (int i = 0; i < 4; ++i) {
      const int c = i * 256 + t;
      const int row = c >> 3, cc = c & 7;       // 8 chunks per 64-elem row
      lds_load16(&A [(size_t)(bm + row) * K + kt + cc * 8], (char*)lA + c * 16);
      lds_load16(&Bt[(size_t)(bn + row) * K + kt + cc * 8], (char*)lB + c * 16);
    }
    __syncthreads();   // compiler emits vmcnt(0) drain before s_barrier
#pragma unroll
    for (int kk = 0; kk < BK; kk += 32) {
      bf16x8 af[4], bfr[4];
#pragma unroll
      for (int m = 0; m < 4; ++m)
        af[m] = *(const bf16x8*)&lA[(wr * 64 + m * 16 + lo) * BK + kk + hi * 8];
#pragma unroll
      for (int n = 0; n < 4; ++n)
        bfr[n] = *(const bf16x8*)&lB[(wc * 64 + n * 16 + lo) * BK + kk + hi * 8];
#pragma unroll
      for (int m = 0; m < 4; ++m)
#pragma unroll
        for (int n = 0; n < 4; ++n)
          acc[m][n] = __builtin_amdgcn_mfma_f32_16x16x32_bf16(af[m], bfr[n], acc[m][n], 0, 0, 0);
    }
    __syncthreads();
  }

  float* Cf = (float*)Cp;
  unsigned short* Cb = (unsigned short*)Cp;
#pragma unroll
  for (int m = 0; m < 4; ++m)
#pragma unroll
    for (int n = 0; n < 4; ++n)
#pragma unroll
      for (int r = 0; r < 4; ++r) {
        const int row = bm + wr * 64 + m * 16 + hi * 4 + r;
        const int col = bn + wc * 64 + n * 16 + lo;
        const size_t idx = (size_t)row * N + col;
        if constexpr (EPI == 0)      Cf[idx] = acc[m][n][r];
        else if constexpr (EPI == 1) Cf[idx] += acc[m][n][r];
        else                         Cb[idx] = f2bf(acc[m][n][r]);
      }
}

extern "C" void kernel_launch(void* const* d_in, const int* in_sizes, int n_in,
                              void* d_out, int out_size, void* d_ws, size_t ws_size,
                              hipStream_t stream) {
  const float* x   = (const float*)d_in[0];
  const float* sel = (const float*)d_in[1];
  const float* ew  = (const float*)d_in[2];   // [4096 k][4096 o]
  const float* wc1 = (const float*)d_in[3];   // [4096][512]
  const float* wc2 = (const float*)d_in[4];   // [512][4096]
  float* out = (float*)d_out;

  // workspace layout (144 MiB peak):
  //   [0,64M)    xw   [8192][4096] bf16
  //   [64M,128M) xm   [8192][4096] bf16  -> later reused as w1t [4096][4096] bf16 (32 MiB)
  //   [128M,136M) tbuf [8192][512] bf16
  //   [136M,140M) w1ct [512][4096] bf16
  //   [140M,144M) w2ct [4096][512] bf16
  char* ws = (char*)d_ws;
  unsigned short* xw   = (unsigned short*)(ws);
  unsigned short* xm   = (unsigned short*)(ws + 67108864);
  unsigned short* w1t  = xm;  // aliases xm: xm is dead before w1t is written
  unsigned short* tbuf = (unsigned short*)(ws + 134217728);
  unsigned short* w1ct = (unsigned short*)(ws + 142606336);
  unsigned short* w2ct = (unsigned short*)(ws + 146800640);

  // 1. routing + scaled bf16 copies of x
  k_route<<<BATCH, 256, 0, stream>>>(x, sel, xw, xm);
  // 2. small weight transposes
  k_transpose_bf16<<<dim3(COMP  / 64, IN_F / 64), 256, 0, stream>>>(wc1, w1ct, IN_F, COMP);
  k_transpose_bf16<<<dim3(OUT_F / 64, COMP / 64), 256, 0, stream>>>(wc2, w2ct, COMP, OUT_F);
  // 3. compress GEMM-1: tbuf(bf16) = xm @ Wc1; xm dead afterwards
  k_gemm_bt<2><<<dim3(COMP / BN, BATCH / BM), 256, 0, stream>>>(xm, w1ct, (void*)tbuf, BATCH, COMP, IN_F);
  // 4. expert weight transpose into space formerly held by xm
  k_transpose_bf16<<<dim3(OUT_F / 64, IN_F / 64), 256, 0, stream>>>(ew, w1t, IN_F, OUT_F);
  // 5. expert GEMM: out = xw @ W1
  k_gemm_bt<0><<<dim3(OUT_F / BN, BATCH / BM), 256, 0, stream>>>(xw, w1t, out, BATCH, OUT_F, IN_F);
  // 6. compress GEMM-2: out += tbuf @ Wc2
  k_gemm_bt<1><<<dim3(OUT_F / BN, BATCH / BM), 256, 0, stream>>>(tbuf, w2ct, out, BATCH, OUT_F, COMP);
}

// Round 6
// 751.918 us; speedup vs baseline: 1.2514x; 1.2514x over previous
//
#include <hip/hip_runtime.h>
#include <hip/hip_bf16.h>
#include <stdint.h>

#define BATCH 8192
#define IN_F  4096
#define OUT_F 4096
#define NFRAG 32
#define FSIZE 128
#define COMP  512

typedef float f32x4 __attribute__((ext_vector_type(4)));
typedef short bf16x8 __attribute__((ext_vector_type(8)));

__device__ __forceinline__ unsigned short f2bf(float f) {
  union { float f; unsigned u; } v; v.f = f;
  return (unsigned short)((v.u + 0x7FFFu + ((v.u >> 16) & 1u)) >> 16);
}
__device__ __forceinline__ unsigned pack2(float a, float b) {
  return (unsigned)f2bf(a) | ((unsigned)f2bf(b) << 16);
}

typedef const __attribute__((address_space(1))) unsigned* as1_u32p;
typedef __attribute__((address_space(3))) unsigned* as3_u32p;

// async global->LDS, 16B per lane; LDS dest must be wave-uniform base + lane*16.
__device__ __forceinline__ void lds_load16(const void* g, void* l) {
  __builtin_amdgcn_global_load_lds((as1_u32p)(uintptr_t)g, (as3_u32p)(uintptr_t)l, 16, 0, 0);
}

// ---------------- routing: probs + scaled bf16 copies ----------------
__global__ __launch_bounds__(256) void k_route(
    const float* __restrict__ x, const float* __restrict__ sel,
    unsigned short* __restrict__ xw, unsigned short* __restrict__ xm) {
  __shared__ float red[256];
  __shared__ float sc[NFRAG];
  const int b = blockIdx.x;
  const int t = threadIdx.x;
  const float* xr = x + (size_t)b * IN_F;
  const int frag = t >> 3;

  float4 v0 = *(const float4*)&xr[t * 16 + 0];
  float4 v1 = *(const float4*)&xr[t * 16 + 4];
  float4 v2 = *(const float4*)&xr[t * 16 + 8];
  float4 v3 = *(const float4*)&xr[t * 16 + 12];
  const float* sw = sel + frag * FSIZE + (t & 7) * 16;
  float4 s0 = *(const float4*)&sw[0];
  float4 s1 = *(const float4*)&sw[4];
  float4 s2 = *(const float4*)&sw[8];
  float4 s3 = *(const float4*)&sw[12];
  float d = v0.x*s0.x + v0.y*s0.y + v0.z*s0.z + v0.w*s0.w
          + v1.x*s1.x + v1.y*s1.y + v1.z*s1.z + v1.w*s1.w
          + v2.x*s2.x + v2.y*s2.y + v2.z*s2.z + v2.w*s2.w
          + v3.x*s3.x + v3.y*s3.y + v3.z*s3.z + v3.w*s3.w;
  red[t] = d;
  __syncthreads();
  if (t < NFRAG) {
    float s = 0.f;
#pragma unroll
    for (int j = 0; j < 8; ++j) s += red[t * 8 + j];
    sc[t] = s;
  }
  __syncthreads();
  float mx = sc[0];
#pragma unroll
  for (int f = 1; f < NFRAG; ++f) mx = fmaxf(mx, sc[f]);
  float den = 0.f;
#pragma unroll
  for (int f = 0; f < NFRAG; ++f) den += __expf(sc[f] - mx);
  const float p = __expf(sc[frag] - mx) / den;
  const float q = 1.f - p;

  const size_t base = (size_t)b * IN_F + (size_t)t * 16;
  uint4 w;
  w.x = pack2(v0.x*p, v0.y*p); w.y = pack2(v0.z*p, v0.w*p);
  w.z = pack2(v1.x*p, v1.y*p); w.w = pack2(v1.z*p, v1.w*p);
  *(uint4*)&xw[base] = w;
  w.x = pack2(v2.x*p, v2.y*p); w.y = pack2(v2.z*p, v2.w*p);
  w.z = pack2(v3.x*p, v3.y*p); w.w = pack2(v3.z*p, v3.w*p);
  *(uint4*)&xw[base + 8] = w;
  w.x = pack2(v0.x*q, v0.y*q); w.y = pack2(v0.z*q, v0.w*q);
  w.z = pack2(v1.x*q, v1.y*q); w.w = pack2(v1.z*q, v1.w*q);
  *(uint4*)&xm[base] = w;
  w.x = pack2(v2.x*q, v2.y*q); w.y = pack2(v2.z*q, v2.w*q);
  w.z = pack2(v3.x*q, v3.y*q); w.w = pack2(v3.z*q, v3.w*q);
  *(uint4*)&xm[base + 8] = w;
}

// ---------------- f32 [R][C] -> bf16 [C][R] tiled transpose-convert ----------------
__global__ __launch_bounds__(256) void k_transpose_bf16(
    const float* __restrict__ src, unsigned short* __restrict__ dst, int R, int C) {
  __shared__ float tile[64][65];
  const int t = threadIdx.x;
  const int c0 = blockIdx.x * 64, r0 = blockIdx.y * 64;
#pragma unroll
  for (int i = 0; i < 4; ++i) {
    const int q = i * 256 + t;
    const int row = q >> 4;
    const int col = (q & 15) << 2;
    float4 v = *(const float4*)&src[(size_t)(r0 + row) * C + c0 + col];
    tile[row][col + 0] = v.x; tile[row][col + 1] = v.y;
    tile[row][col + 2] = v.z; tile[row][col + 3] = v.w;
  }
  __syncthreads();
#pragma unroll
  for (int i = 0; i < 4; ++i) {
    const int q = i * 256 + t;
    const int orow = q >> 4;
    const int oc = (q & 15) << 2;
    ushort4 o;
    o.x = f2bf(tile[oc + 0][orow]);
    o.y = f2bf(tile[oc + 1][orow]);
    o.z = f2bf(tile[oc + 2][orow]);
    o.w = f2bf(tile[oc + 3][orow]);
    *(ushort4*)&dst[(size_t)(c0 + orow) * R + r0 + oc] = o;
  }
}

// ---------------- 128^2 bf16 GEMM (m97 structure) — used for the N=512 GEMM ----------------
#define BM 128
#define BN 128
#define BK 64

template <int EPI>  // 0 = store f32, 1 = +=, 2 = store bf16
__global__ __launch_bounds__(256) void k_gemm_bt(
    const unsigned short* __restrict__ A, const unsigned short* __restrict__ Bt,
    void* __restrict__ Cp, int M, int N, int K) {
  __shared__ unsigned short lA[BM * BK];
  __shared__ unsigned short lB[BN * BK];
  const int t = threadIdx.x;
  const int lane = t & 63;
  const int wave = t >> 6;
  const int wr = wave >> 1, wc = wave & 1;
  const int hi = lane >> 4, lo = lane & 15;
  const int bm = blockIdx.y * BM, bn = blockIdx.x * BN;

  f32x4 acc[4][4] = {};

  for (int kt = 0; kt < K; kt += BK) {
#pragma unroll
    for (int i = 0; i < 4; ++i) {
      const int c = i * 256 + t;
      const int row = c >> 3, cc = c & 7;
      lds_load16(&A [(size_t)(bm + row) * K + kt + cc * 8], (char*)lA + c * 16);
      lds_load16(&Bt[(size_t)(bn + row) * K + kt + cc * 8], (char*)lB + c * 16);
    }
    __syncthreads();
#pragma unroll
    for (int kk = 0; kk < BK; kk += 32) {
      bf16x8 af[4], bfr[4];
#pragma unroll
      for (int m = 0; m < 4; ++m)
        af[m] = *(const bf16x8*)&lA[(wr * 64 + m * 16 + lo) * BK + kk + hi * 8];
#pragma unroll
      for (int n = 0; n < 4; ++n)
        bfr[n] = *(const bf16x8*)&lB[(wc * 64 + n * 16 + lo) * BK + kk + hi * 8];
#pragma unroll
      for (int m = 0; m < 4; ++m)
#pragma unroll
        for (int n = 0; n < 4; ++n)
          acc[m][n] = __builtin_amdgcn_mfma_f32_16x16x32_bf16(af[m], bfr[n], acc[m][n], 0, 0, 0);
    }
    __syncthreads();
  }

  float* Cf = (float*)Cp;
  unsigned short* Cb = (unsigned short*)Cp;
#pragma unroll
  for (int m = 0; m < 4; ++m)
#pragma unroll
    for (int n = 0; n < 4; ++n)
#pragma unroll
      for (int r = 0; r < 4; ++r) {
        const int row = bm + wr * 64 + m * 16 + hi * 4 + r;
        const int col = bn + wc * 64 + n * 16 + lo;
        const size_t idx = (size_t)row * N + col;
        if constexpr (EPI == 0)      Cf[idx] = acc[m][n][r];
        else if constexpr (EPI == 1) Cf[idx] += acc[m][n][r];
        else                         Cb[idx] = f2bf(acc[m][n][r]);
      }
}

// ---------------- 256^2 deep-pipelined bf16 GEMM, ring-3 K-tile buffers ----------------
// C[M][N] = A[M][K] @ Bt[N][K]^T.  BK=32, 512 threads (8 waves, 2Mx4N), LDS 96 KiB.
// Pipeline: compute tile t from slot t%3 while tile t+2 streams into slot (t+2)%3.
// Counted s_waitcnt vmcnt(4) at tile boundary (never 0 in steady state) + RAW s_barrier
// (avoids compiler's vmcnt(0) drain). LDS k-slot XOR swizzle (pre-swizzled global source
// + swizzled ds_read; involution s^=( (row>>1)&3 )) -> spreads lanes across banks.
#define G_SLOT  16384            // one matrix K-tile: 256 rows x 32 cols x 2B
#define G_STRIDE 32768           // A slot + B slot
#define G_LDS   98304            // 3 ring slots

template <int EPI>  // 0 = store f32, 1 = += f32
__global__ __launch_bounds__(512, 2) void k_gemm256(
    const unsigned short* __restrict__ A, const unsigned short* __restrict__ Bt,
    float* __restrict__ C, int M, int N, int K) {
  extern __shared__ char lds[];
  const int t = threadIdx.x;
  const int lane = t & 63;
  const int wid = t >> 6;
  const int wr = wid >> 2;              // 0..1 : owns rows wr*128..+128
  const int wc = wid & 3;               // 0..3 : owns cols wc*64..+64
  const int lo = lane & 15, hi = lane >> 4;

  // XCD-chunked tile remap (gridDim.x % 8 == 0 guaranteed by launches)
  const int nwg = gridDim.x;
  const int chunk = nwg >> 3;
  const int remap = ((int)blockIdx.x & 7) * chunk + ((int)blockIdx.x >> 3);
  const int nx = N >> 8;
  const int bm = (remap / nx) << 8;
  const int bn = (remap % nx) << 8;

  const int NT = K >> 5;

  // staging: 1024 16B-chunks per matrix tile; thread handles chunks t and t+512.
  // chunk c -> LDS (row=c>>2, phys slot=c&3); holds data k-slot sd = sp ^ ((row>>1)&3).
  const int c0 = t,       r0 = c0 >> 2, s0 = (c0 & 3) ^ ((r0 >> 1) & 3);
  const int c1 = t + 512, r1 = c1 >> 2, s1 = (c1 & 3) ^ ((r1 >> 1) & 3);
  const unsigned short* Ap0 = A  + (size_t)(bm + r0) * K + s0 * 8;
  const unsigned short* Ap1 = A  + (size_t)(bm + r1) * K + s1 * 8;
  const unsigned short* Bp0 = Bt + (size_t)(bn + r0) * K + s0 * 8;
  const unsigned short* Bp1 = Bt + (size_t)(bn + r1) * K + s1 * 8;

  // ds_read bases: row-major [256][32] bf16 per slot; swizzled k-slot byte offset
  const int ksl = ((hi ^ ((lo >> 1) & 3)) << 4);
  const int aBase = wr * 8192 + lo * 64 + ksl;            // + m*1024
  const int bBase = G_SLOT + wc * 4096 + lo * 64 + ksl;   // + n*1024

  f32x4 acc[8][4] = {};

#define STAGE(tt_) do {                                            \
    char* _b = lds + ((tt_) % 3) * G_STRIDE;                       \
    const int _kt = (tt_) << 5;                                    \
    lds_load16(Ap0 + _kt, _b + c0 * 16);                           \
    lds_load16(Ap1 + _kt, _b + c1 * 16);                           \
    lds_load16(Bp0 + _kt, _b + G_SLOT + c0 * 16);                  \
    lds_load16(Bp1 + _kt, _b + G_SLOT + c1 * 16);                  \
  } while (0)

  // prologue: tiles 0,1 in flight; wait tile 0 (vmcnt(4) leaves tile 1's 4 loads pending)
  STAGE(0);
  STAGE(1);
  asm volatile("s_waitcnt vmcnt(4)" ::: "memory");
  __builtin_amdgcn_sched_barrier(0);
  __builtin_amdgcn_s_barrier();
  __builtin_amdgcn_sched_barrier(0);

  for (int tt = 0; tt < NT; ++tt) {
    if (tt + 2 < NT) STAGE(tt + 2);
    const char* sa = lds + (tt % 3) * G_STRIDE;
    bf16x8 a[8], b[4];
#pragma unroll
    for (int n = 0; n < 4; ++n) b[n] = *(const bf16x8*)(sa + bBase + n * 1024);
#pragma unroll
    for (int m = 0; m < 8; ++m) a[m] = *(const bf16x8*)(sa + aBase + m * 1024);
    asm volatile("s_waitcnt lgkmcnt(0)" ::: "memory");
    __builtin_amdgcn_sched_barrier(0);
    __builtin_amdgcn_s_setprio(1);
#pragma unroll
    for (int m = 0; m < 8; ++m)
#pragma unroll
      for (int n = 0; n < 4; ++n)
        acc[m][n] = __builtin_amdgcn_mfma_f32_16x16x32_bf16(a[m], b[n], acc[m][n], 0, 0, 0);
    __builtin_amdgcn_s_setprio(0);
    if (tt + 1 < NT) {
      if (tt + 2 < NT) { asm volatile("s_waitcnt vmcnt(4)" ::: "memory"); }
      else             { asm volatile("s_waitcnt vmcnt(0)" ::: "memory"); }
      __builtin_amdgcn_sched_barrier(0);
      __builtin_amdgcn_s_barrier();
      __builtin_amdgcn_sched_barrier(0);
    }
  }
#undef STAGE

#pragma unroll
  for (int m = 0; m < 8; ++m)
#pragma unroll
    for (int n = 0; n < 4; ++n)
#pragma unroll
      for (int r = 0; r < 4; ++r) {
        const int row = bm + wr * 128 + m * 16 + hi * 4 + r;
        const int col = bn + wc * 64 + n * 16 + lo;
        const size_t idx = (size_t)row * N + col;
        if constexpr (EPI == 0) C[idx] = acc[m][n][r];
        else                    C[idx] += acc[m][n][r];
      }
}

extern "C" void kernel_launch(void* const* d_in, const int* in_sizes, int n_in,
                              void* d_out, int out_size, void* d_ws, size_t ws_size,
                              hipStream_t stream) {
  const float* x   = (const float*)d_in[0];
  const float* sel = (const float*)d_in[1];
  const float* ew  = (const float*)d_in[2];   // [4096 k][4096 o]
  const float* wc1 = (const float*)d_in[3];   // [4096][512]
  const float* wc2 = (const float*)d_in[4];   // [512][4096]
  float* out = (float*)d_out;

  // workspace (144 MiB peak)
  char* ws = (char*)d_ws;
  unsigned short* xw   = (unsigned short*)(ws);
  unsigned short* xm   = (unsigned short*)(ws + 67108864);
  unsigned short* w1t  = xm;  // aliases xm: xm dead before w1t written
  unsigned short* tbuf = (unsigned short*)(ws + 134217728);
  unsigned short* w1ct = (unsigned short*)(ws + 142606336);
  unsigned short* w2ct = (unsigned short*)(ws + 146800640);

  // raise dynamic-LDS limit for the 96 KiB kernels (host-side, graph-capture-safe)
  (void)hipFuncSetAttribute((const void*)k_gemm256<0>,
                            hipFuncAttributeMaxDynamicSharedMemorySize, G_LDS);
  (void)hipFuncSetAttribute((const void*)k_gemm256<1>,
                            hipFuncAttributeMaxDynamicSharedMemorySize, G_LDS);

  // 1. routing + scaled bf16 copies
  k_route<<<BATCH, 256, 0, stream>>>(x, sel, xw, xm);
  // 2. small weight transposes
  k_transpose_bf16<<<dim3(COMP  / 64, IN_F / 64), 256, 0, stream>>>(wc1, w1ct, IN_F, COMP);
  k_transpose_bf16<<<dim3(OUT_F / 64, COMP / 64), 256, 0, stream>>>(wc2, w2ct, COMP, OUT_F);
  // 3. compress GEMM-1 (N=512, stays on 128^2): tbuf = xm @ Wc1 ; xm dead after
  k_gemm_bt<2><<<dim3(COMP / BN, BATCH / BM), 256, 0, stream>>>(xm, w1ct, (void*)tbuf, BATCH, COMP, IN_F);
  // 4. expert weight transpose into xm's space
  k_transpose_bf16<<<dim3(OUT_F / 64, IN_F / 64), 256, 0, stream>>>(ew, w1t, IN_F, OUT_F);
  // 5. expert GEMM (deep-pipelined 256^2): out = xw @ W1   (grid 512 = 32x16, %8==0)
  k_gemm256<0><<<(BATCH / 256) * (OUT_F / 256), 512, G_LDS, stream>>>(xw, w1t, out, BATCH, OUT_F, IN_F);
  // 6. compress GEMM-2 (256^2): out += tbuf @ Wc2   (K=512 -> 16 K-tiles)
  k_gemm256<1><<<(BATCH / 256) * (OUT_F / 256), 512, G_LDS, stream>>>(tbuf, w2ct, out, BATCH, OUT_F, COMP);
}

// Round 7
// 675.253 us; speedup vs baseline: 1.3935x; 1.1135x over previous
//
#include <hip/hip_runtime.h>
#include <hip/hip_bf16.h>
#include <stdint.h>

#define BATCH 8192
#define IN_F  4096
#define OUT_F 4096
#define NFRAG 32
#define FSIZE 128
#define COMP  512
#define KCAT  4608   // IN_F + COMP

typedef float f32x4 __attribute__((ext_vector_type(4)));
typedef short bf16x8 __attribute__((ext_vector_type(8)));

__device__ __forceinline__ unsigned short f2bf(float f) {
  union { float f; unsigned u; } v; v.f = f;
  return (unsigned short)((v.u + 0x7FFFu + ((v.u >> 16) & 1u)) >> 16);
}
__device__ __forceinline__ unsigned pack2(float a, float b) {
  return (unsigned)f2bf(a) | ((unsigned)f2bf(b) << 16);
}

typedef const __attribute__((address_space(1))) unsigned* as1_u32p;
typedef __attribute__((address_space(3))) unsigned* as3_u32p;

__device__ __forceinline__ void lds_load16(const void* g, void* l) {
  __builtin_amdgcn_global_load_lds((as1_u32p)(uintptr_t)g, (as3_u32p)(uintptr_t)l, 16, 0, 0);
}

// ---------------- routing: probs + scaled bf16 copies ----------------
// xw goes into xcat cols 0..4095 (row stride KCAT); xm dense stride IN_F.
__global__ __launch_bounds__(256) void k_route(
    const float* __restrict__ x, const float* __restrict__ sel,
    unsigned short* __restrict__ xw, unsigned short* __restrict__ xm) {
  __shared__ float red[256];
  __shared__ float sc[NFRAG];
  const int b = blockIdx.x;
  const int t = threadIdx.x;
  const float* xr = x + (size_t)b * IN_F;
  const int frag = t >> 3;

  float4 v0 = *(const float4*)&xr[t * 16 + 0];
  float4 v1 = *(const float4*)&xr[t * 16 + 4];
  float4 v2 = *(const float4*)&xr[t * 16 + 8];
  float4 v3 = *(const float4*)&xr[t * 16 + 12];
  const float* sw = sel + frag * FSIZE + (t & 7) * 16;
  float4 s0 = *(const float4*)&sw[0];
  float4 s1 = *(const float4*)&sw[4];
  float4 s2 = *(const float4*)&sw[8];
  float4 s3 = *(const float4*)&sw[12];
  float d = v0.x*s0.x + v0.y*s0.y + v0.z*s0.z + v0.w*s0.w
          + v1.x*s1.x + v1.y*s1.y + v1.z*s1.z + v1.w*s1.w
          + v2.x*s2.x + v2.y*s2.y + v2.z*s2.z + v2.w*s2.w
          + v3.x*s3.x + v3.y*s3.y + v3.z*s3.z + v3.w*s3.w;
  red[t] = d;
  __syncthreads();
  if (t < NFRAG) {
    float s = 0.f;
#pragma unroll
    for (int j = 0; j < 8; ++j) s += red[t * 8 + j];
    sc[t] = s;
  }
  __syncthreads();
  float mx = sc[0];
#pragma unroll
  for (int f = 1; f < NFRAG; ++f) mx = fmaxf(mx, sc[f]);
  float den = 0.f;
#pragma unroll
  for (int f = 0; f < NFRAG; ++f) den += __expf(sc[f] - mx);
  const float p = __expf(sc[frag] - mx) / den;
  const float q = 1.f - p;

  const size_t bw = (size_t)b * KCAT + (size_t)t * 16;
  const size_t bm_ = (size_t)b * IN_F + (size_t)t * 16;
  uint4 w;
  w.x = pack2(v0.x*p, v0.y*p); w.y = pack2(v0.z*p, v0.w*p);
  w.z = pack2(v1.x*p, v1.y*p); w.w = pack2(v1.z*p, v1.w*p);
  *(uint4*)&xw[bw] = w;
  w.x = pack2(v2.x*p, v2.y*p); w.y = pack2(v2.z*p, v2.w*p);
  w.z = pack2(v3.x*p, v3.y*p); w.w = pack2(v3.z*p, v3.w*p);
  *(uint4*)&xw[bw + 8] = w;
  w.x = pack2(v0.x*q, v0.y*q); w.y = pack2(v0.z*q, v0.w*q);
  w.z = pack2(v1.x*q, v1.y*q); w.w = pack2(v1.z*q, v1.w*q);
  *(uint4*)&xm[bm_] = w;
  w.x = pack2(v2.x*q, v2.y*q); w.y = pack2(v2.z*q, v2.w*q);
  w.z = pack2(v3.x*q, v3.y*q); w.w = pack2(v3.z*q, v3.w*q);
  *(uint4*)&xm[bm_ + 8] = w;
}

// ---------------- f32 [R][C] -> bf16 [C][R] transpose-convert, strided dst ----------------
__global__ __launch_bounds__(256) void k_transpose_bf16(
    const float* __restrict__ src, unsigned short* __restrict__ dst,
    int R, int C, int ldd) {
  __shared__ float tile[64][65];
  const int t = threadIdx.x;
  const int c0 = blockIdx.x * 64, r0 = blockIdx.y * 64;
#pragma unroll
  for (int i = 0; i < 4; ++i) {
    const int q = i * 256 + t;
    const int row = q >> 4;
    const int col = (q & 15) << 2;
    float4 v = *(const float4*)&src[(size_t)(r0 + row) * C + c0 + col];
    tile[row][col + 0] = v.x; tile[row][col + 1] = v.y;
    tile[row][col + 2] = v.z; tile[row][col + 3] = v.w;
  }
  __syncthreads();
#pragma unroll
  for (int i = 0; i < 4; ++i) {
    const int q = i * 256 + t;
    const int orow = q >> 4;
    const int oc = (q & 15) << 2;
    ushort4 o;
    o.x = f2bf(tile[oc + 0][orow]);
    o.y = f2bf(tile[oc + 1][orow]);
    o.z = f2bf(tile[oc + 2][orow]);
    o.w = f2bf(tile[oc + 3][orow]);
    *(ushort4*)&dst[(size_t)(c0 + orow) * ldd + r0 + oc] = o;
  }
}

// ---------------- 128^2 bf16 GEMM (m97 structure) — G2 (N=512) ----------------
#define BM 128
#define BN 128
#define BK 64

// EPI: 2 = store bf16 (only instantiation used)
template <int EPI>
__global__ __launch_bounds__(256) void k_gemm_bt(
    const unsigned short* __restrict__ A, int lda,
    const unsigned short* __restrict__ Bt, int ldb,
    void* __restrict__ Cp, int ldc, int M, int N, int K) {
  __shared__ unsigned short lA[BM * BK];
  __shared__ unsigned short lB[BN * BK];
  const int t = threadIdx.x;
  const int lane = t & 63;
  const int wave = t >> 6;
  const int wr = wave >> 1, wc = wave & 1;
  const int hi = lane >> 4, lo = lane & 15;
  const int bm = blockIdx.y * BM, bn = blockIdx.x * BN;

  f32x4 acc[4][4] = {};

  for (int kt = 0; kt < K; kt += BK) {
#pragma unroll
    for (int i = 0; i < 4; ++i) {
      const int c = i * 256 + t;
      const int row = c >> 3, cc = c & 7;
      lds_load16(&A [(size_t)(bm + row) * lda + kt + cc * 8], (char*)lA + c * 16);
      lds_load16(&Bt[(size_t)(bn + row) * ldb + kt + cc * 8], (char*)lB + c * 16);
    }
    __syncthreads();
#pragma unroll
    for (int kk = 0; kk < BK; kk += 32) {
      bf16x8 af[4], bfr[4];
#pragma unroll
      for (int m = 0; m < 4; ++m)
        af[m] = *(const bf16x8*)&lA[(wr * 64 + m * 16 + lo) * BK + kk + hi * 8];
#pragma unroll
      for (int n = 0; n < 4; ++n)
        bfr[n] = *(const bf16x8*)&lB[(wc * 64 + n * 16 + lo) * BK + kk + hi * 8];
#pragma unroll
      for (int m = 0; m < 4; ++m)
#pragma unroll
        for (int n = 0; n < 4; ++n)
          acc[m][n] = __builtin_amdgcn_mfma_f32_16x16x32_bf16(af[m], bfr[n], acc[m][n], 0, 0, 0);
    }
    __syncthreads();
  }

  float* Cf = (float*)Cp;
  unsigned short* Cb = (unsigned short*)Cp;
#pragma unroll
  for (int m = 0; m < 4; ++m)
#pragma unroll
    for (int n = 0; n < 4; ++n)
#pragma unroll
      for (int r = 0; r < 4; ++r) {
        const int row = bm + wr * 64 + m * 16 + hi * 4 + r;
        const int col = bn + wc * 64 + n * 16 + lo;
        const size_t idx = (size_t)row * ldc + col;
        if constexpr (EPI == 0)      Cf[idx] = acc[m][n][r];
        else if constexpr (EPI == 1) Cf[idx] += acc[m][n][r];
        else                         Cb[idx] = f2bf(acc[m][n][r]);
      }
}

// ---------------- 256^2 deep-pipelined bf16 GEMM, ring-3 K-tile buffers ----------------
// Overlap model: ds_reads and MFMAs are NOT explicitly fenced; the compiler emits
// counted lgkmcnt so reads pipeline under MFMAs (m97 asm evidence). Raw s_barrier
// (one per K-tile) + counted vmcnt(4) keep the global pipeline 2 tiles deep.
#define G_SLOT  16384
#define G_STRIDE 32768
#define G_LDS   98304

__global__ __launch_bounds__(512, 2) void k_gemm256(
    const unsigned short* __restrict__ A, int lda,
    const unsigned short* __restrict__ Bt, int ldb,
    float* __restrict__ C, int M, int N, int K) {
  extern __shared__ char lds[];
  const int t = threadIdx.x;
  const int lane = t & 63;
  const int wid = t >> 6;
  const int wr = wid >> 2;
  const int wc = wid & 3;
  const int lo = lane & 15, hi = lane >> 4;

  const int nwg = gridDim.x;
  const int chunk = nwg >> 3;
  const int remap = ((int)blockIdx.x & 7) * chunk + ((int)blockIdx.x >> 3);
  const int nx = N >> 8;
  const int bm = (remap / nx) << 8;
  const int bn = (remap % nx) << 8;

  const int NT = K >> 5;

  // staging: chunk c -> LDS (row=c>>2, phys slot=c&3); data k-slot = (c&3)^((row>>1)&3)
  const int c0 = t,       r0 = c0 >> 2, s0 = (c0 & 3) ^ ((r0 >> 1) & 3);
  const int c1 = t + 512, r1 = c1 >> 2, s1 = (c1 & 3) ^ ((r1 >> 1) & 3);
  const unsigned short* Ap0 = A  + (size_t)(bm + r0) * lda + s0 * 8;
  const unsigned short* Ap1 = A  + (size_t)(bm + r1) * lda + s1 * 8;
  const unsigned short* Bp0 = Bt + (size_t)(bn + r0) * ldb + s0 * 8;
  const unsigned short* Bp1 = Bt + (size_t)(bn + r1) * ldb + s1 * 8;

  const int ksl = ((hi ^ ((lo >> 1) & 3)) << 4);
  const int aBase = wr * 8192 + lo * 64 + ksl;            // + m*1024
  const int bBase = G_SLOT + wc * 4096 + lo * 64 + ksl;   // + n*1024

  f32x4 acc[8][4] = {};

#define STAGE(tt_) do {                                            \
    char* _b = lds + ((tt_) % 3) * G_STRIDE;                       \
    const int _kt = (tt_) << 5;                                    \
    lds_load16(Ap0 + _kt, _b + c0 * 16);                           \
    lds_load16(Ap1 + _kt, _b + c1 * 16);                           \
    lds_load16(Bp0 + _kt, _b + G_SLOT + c0 * 16);                  \
    lds_load16(Bp1 + _kt, _b + G_SLOT + c1 * 16);                  \
  } while (0)

  STAGE(0);
  STAGE(1);
  asm volatile("s_waitcnt vmcnt(4)" ::: "memory");
  __builtin_amdgcn_sched_barrier(0);
  __builtin_amdgcn_s_barrier();
  __builtin_amdgcn_sched_barrier(0);

  for (int tt = 0; tt < NT; ++tt) {
    if (tt + 2 < NT) STAGE(tt + 2);
    __builtin_amdgcn_s_setprio(1);
    const char* sa = lds + (tt % 3) * G_STRIDE;
    bf16x8 a[8], b[4];
#pragma unroll
    for (int n = 0; n < 4; ++n) b[n] = *(const bf16x8*)(sa + bBase + n * 1024);
#pragma unroll
    for (int m = 0; m < 8; ++m) a[m] = *(const bf16x8*)(sa + aBase + m * 1024);
    // no explicit lgkmcnt(0): compiler interleaves reads under MFMAs w/ counted waits
#pragma unroll
    for (int m = 0; m < 8; ++m)
#pragma unroll
      for (int n = 0; n < 4; ++n)
        acc[m][n] = __builtin_amdgcn_mfma_f32_16x16x32_bf16(a[m], b[n], acc[m][n], 0, 0, 0);
    __builtin_amdgcn_s_setprio(0);
    if (tt + 1 < NT) {
      if (tt + 2 < NT) { asm volatile("s_waitcnt vmcnt(4)" ::: "memory"); }
      else             { asm volatile("s_waitcnt vmcnt(0)" ::: "memory"); }
      __builtin_amdgcn_sched_barrier(0);
      __builtin_amdgcn_s_barrier();
      __builtin_amdgcn_sched_barrier(0);
    }
  }
#undef STAGE

#pragma unroll
  for (int m = 0; m < 8; ++m)
#pragma unroll
    for (int n = 0; n < 4; ++n)
#pragma unroll
      for (int r = 0; r < 4; ++r) {
        const int row = bm + wr * 128 + m * 16 + hi * 4 + r;
        const int col = bn + wc * 64 + n * 16 + lo;
        C[(size_t)row * N + col] = acc[m][n][r];
      }
}

extern "C" void kernel_launch(void* const* d_in, const int* in_sizes, int n_in,
                              void* d_out, int out_size, void* d_ws, size_t ws_size,
                              hipStream_t stream) {
  const float* x   = (const float*)d_in[0];
  const float* sel = (const float*)d_in[1];
  const float* ew  = (const float*)d_in[2];   // [4096 k][4096 o]
  const float* wc1 = (const float*)d_in[3];   // [4096][512]
  const float* wc2 = (const float*)d_in[4];   // [512][4096]
  float* out = (float*)d_out;

  // workspace (~140 MiB peak):
  //   xcat  @ 0          : [8192][4608] bf16 (75.5 MB)  cols 0-4095 = xw, 4096+ = tbuf
  //   xm    @ 75497472   : [8192][4096] bf16 (64 MB)    dead after G2
  //   btcat @ 75497472   : [4096][4608] bf16 (37.7 MB)  aliases xm
  //   w1ct  @ 142606336  : [512][4096]  bf16 (4 MB)
  char* ws = (char*)d_ws;
  unsigned short* xcat  = (unsigned short*)(ws);
  unsigned short* xm    = (unsigned short*)(ws + 75497472);
  unsigned short* btcat = (unsigned short*)(ws + 75497472);
  unsigned short* w1ct  = (unsigned short*)(ws + 142606336);

  (void)hipFuncSetAttribute((const void*)k_gemm256,
                            hipFuncAttributeMaxDynamicSharedMemorySize, G_LDS);

  // 1. routing: xw -> xcat cols 0-4095 (stride KCAT), xm dense
  k_route<<<BATCH, 256, 0, stream>>>(x, sel, xcat, xm);
  // 2. wc1^T for G2
  k_transpose_bf16<<<dim3(COMP / 64, IN_F / 64), 256, 0, stream>>>(wc1, w1ct, IN_F, COMP, IN_F);
  // 3. G2: tbuf = xm @ Wc1 -> xcat cols 4096+ (bf16, ldc=KCAT); xm dead after
  k_gemm_bt<2><<<dim3(COMP / BN, BATCH / BM), 256, 0, stream>>>(
      xm, IN_F, w1ct, IN_F, (void*)(xcat + IN_F), KCAT, BATCH, COMP, IN_F);
  // 4. W1^T -> btcat cols 0-4095 (into xm's space)
  k_transpose_bf16<<<dim3(OUT_F / 64, IN_F / 64), 256, 0, stream>>>(ew, btcat, IN_F, OUT_F, KCAT);
  // 5. Wc2^T -> btcat cols 4096+
  k_transpose_bf16<<<dim3(OUT_F / 64, COMP / 64), 256, 0, stream>>>(wc2, btcat + IN_F, COMP, OUT_F, KCAT);
  // 6. merged GEMM: out = xcat @ btcat^T   (M=8192, N=4096, K=4608; grid 512 %8==0)
  k_gemm256<<<(BATCH / 256) * (OUT_F / 256), 512, G_LDS, stream>>>(
      xcat, KCAT, btcat, KCAT, out, BATCH, OUT_F, KCAT);
}

// Round 9
// 655.993 us; speedup vs baseline: 1.4344x; 1.0294x over previous
//
#include <hip/hip_runtime.h>
#include <hip/hip_bf16.h>
#include <stdint.h>

#define BATCH 8192
#define IN_F  4096
#define OUT_F 4096
#define NFRAG 32
#define FSIZE 128
#define COMP  512
#define KCAT  4608   // IN_F + COMP

typedef float f32x4 __attribute__((ext_vector_type(4)));
typedef short bf16x8 __attribute__((ext_vector_type(8)));

__device__ __forceinline__ unsigned short f2bf(float f) {
  union { float f; unsigned u; } v; v.f = f;
  return (unsigned short)((v.u + 0x7FFFu + ((v.u >> 16) & 1u)) >> 16);
}
__device__ __forceinline__ unsigned pack2(float a, float b) {
  return (unsigned)f2bf(a) | ((unsigned)f2bf(b) << 16);
}

typedef const __attribute__((address_space(1))) unsigned* as1_u32p;
typedef __attribute__((address_space(3))) unsigned* as3_u32p;

__device__ __forceinline__ void lds_load16(const void* g, void* l) {
  __builtin_amdgcn_global_load_lds((as1_u32p)(uintptr_t)g, (as3_u32p)(uintptr_t)l, 16, 0, 0);
}

// ---------------- routing: probs + scaled bf16 copies ----------------
__global__ __launch_bounds__(256) void k_route(
    const float* __restrict__ x, const float* __restrict__ sel,
    unsigned short* __restrict__ xw, unsigned short* __restrict__ xm) {
  __shared__ float red[256];
  __shared__ float sc[NFRAG];
  const int b = blockIdx.x;
  const int t = threadIdx.x;
  const float* xr = x + (size_t)b * IN_F;
  const int frag = t >> 3;

  float4 v0 = *(const float4*)&xr[t * 16 + 0];
  float4 v1 = *(const float4*)&xr[t * 16 + 4];
  float4 v2 = *(const float4*)&xr[t * 16 + 8];
  float4 v3 = *(const float4*)&xr[t * 16 + 12];
  const float* sw = sel + frag * FSIZE + (t & 7) * 16;
  float4 s0 = *(const float4*)&sw[0];
  float4 s1 = *(const float4*)&sw[4];
  float4 s2 = *(const float4*)&sw[8];
  float4 s3 = *(const float4*)&sw[12];
  float d = v0.x*s0.x + v0.y*s0.y + v0.z*s0.z + v0.w*s0.w
          + v1.x*s1.x + v1.y*s1.y + v1.z*s1.z + v1.w*s1.w
          + v2.x*s2.x + v2.y*s2.y + v2.z*s2.z + v2.w*s2.w
          + v3.x*s3.x + v3.y*s3.y + v3.z*s3.z + v3.w*s3.w;
  red[t] = d;
  __syncthreads();
  if (t < NFRAG) {
    float s = 0.f;
#pragma unroll
    for (int j = 0; j < 8; ++j) s += red[t * 8 + j];
    sc[t] = s;
  }
  __syncthreads();
  float mx = sc[0];
#pragma unroll
  for (int f = 1; f < NFRAG; ++f) mx = fmaxf(mx, sc[f]);
  float den = 0.f;
#pragma unroll
  for (int f = 0; f < NFRAG; ++f) den += __expf(sc[f] - mx);
  const float p = __expf(sc[frag] - mx) / den;
  const float q = 1.f - p;

  const size_t bw = (size_t)b * KCAT + (size_t)t * 16;
  const size_t bm_ = (size_t)b * IN_F + (size_t)t * 16;
  uint4 w;
  w.x = pack2(v0.x*p, v0.y*p); w.y = pack2(v0.z*p, v0.w*p);
  w.z = pack2(v1.x*p, v1.y*p); w.w = pack2(v1.z*p, v1.w*p);
  *(uint4*)&xw[bw] = w;
  w.x = pack2(v2.x*p, v2.y*p); w.y = pack2(v2.z*p, v2.w*p);
  w.z = pack2(v3.x*p, v3.y*p); w.w = pack2(v3.z*p, v3.w*p);
  *(uint4*)&xw[bw + 8] = w;
  w.x = pack2(v0.x*q, v0.y*q); w.y = pack2(v0.z*q, v0.w*q);
  w.z = pack2(v1.x*q, v1.y*q); w.w = pack2(v1.z*q, v1.w*q);
  *(uint4*)&xm[bm_] = w;
  w.x = pack2(v2.x*q, v2.y*q); w.y = pack2(v2.z*q, v2.w*q);
  w.z = pack2(v3.x*q, v3.y*q); w.w = pack2(v3.z*q, v3.w*q);
  *(uint4*)&xm[bm_ + 8] = w;
}

// ---------------- f32 [R][C] -> bf16 [C][R] transpose-convert, strided dst ----------------
__global__ __launch_bounds__(256) void k_transpose_bf16(
    const float* __restrict__ src, unsigned short* __restrict__ dst,
    int R, int C, int ldd) {
  __shared__ float tile[64][65];
  const int t = threadIdx.x;
  const int c0 = blockIdx.x * 64, r0 = blockIdx.y * 64;
#pragma unroll
  for (int i = 0; i < 4; ++i) {
    const int q = i * 256 + t;
    const int row = q >> 4;
    const int col = (q & 15) << 2;
    float4 v = *(const float4*)&src[(size_t)(r0 + row) * C + c0 + col];
    tile[row][col + 0] = v.x; tile[row][col + 1] = v.y;
    tile[row][col + 2] = v.z; tile[row][col + 3] = v.w;
  }
  __syncthreads();
#pragma unroll
  for (int i = 0; i < 4; ++i) {
    const int q = i * 256 + t;
    const int orow = q >> 4;
    const int oc = (q & 15) << 2;
    ushort4 o;
    o.x = f2bf(tile[oc + 0][orow]);
    o.y = f2bf(tile[oc + 1][orow]);
    o.z = f2bf(tile[oc + 2][orow]);
    o.w = f2bf(tile[oc + 3][orow]);
    *(ushort4*)&dst[(size_t)(c0 + orow) * ldd + r0 + oc] = o;
  }
}

// ---------------- 128^2 bf16 GEMM (m97 structure) — G2 (N=512) ----------------
#define BM 128
#define BN 128
#define BK 64

template <int EPI>
__global__ __launch_bounds__(256) void k_gemm_bt(
    const unsigned short* __restrict__ A, int lda,
    const unsigned short* __restrict__ Bt, int ldb,
    void* __restrict__ Cp, int ldc, int M, int N, int K) {
  __shared__ unsigned short lA[BM * BK];
  __shared__ unsigned short lB[BN * BK];
  const int t = threadIdx.x;
  const int lane = t & 63;
  const int wave = t >> 6;
  const int wr = wave >> 1, wc = wave & 1;
  const int hi = lane >> 4, lo = lane & 15;
  const int bm = blockIdx.y * BM, bn = blockIdx.x * BN;

  f32x4 acc[4][4] = {};

  for (int kt = 0; kt < K; kt += BK) {
#pragma unroll
    for (int i = 0; i < 4; ++i) {
      const int c = i * 256 + t;
      const int row = c >> 3, cc = c & 7;
      lds_load16(&A [(size_t)(bm + row) * lda + kt + cc * 8], (char*)lA + c * 16);
      lds_load16(&Bt[(size_t)(bn + row) * ldb + kt + cc * 8], (char*)lB + c * 16);
    }
    __syncthreads();
#pragma unroll
    for (int kk = 0; kk < BK; kk += 32) {
      bf16x8 af[4], bfr[4];
#pragma unroll
      for (int m = 0; m < 4; ++m)
        af[m] = *(const bf16x8*)&lA[(wr * 64 + m * 16 + lo) * BK + kk + hi * 8];
#pragma unroll
      for (int n = 0; n < 4; ++n)
        bfr[n] = *(const bf16x8*)&lB[(wc * 64 + n * 16 + lo) * BK + kk + hi * 8];
#pragma unroll
      for (int m = 0; m < 4; ++m)
#pragma unroll
        for (int n = 0; n < 4; ++n)
          acc[m][n] = __builtin_amdgcn_mfma_f32_16x16x32_bf16(af[m], bfr[n], acc[m][n], 0, 0, 0);
    }
    __syncthreads();
  }

  float* Cf = (float*)Cp;
  unsigned short* Cb = (unsigned short*)Cp;
#pragma unroll
  for (int m = 0; m < 4; ++m)
#pragma unroll
    for (int n = 0; n < 4; ++n)
#pragma unroll
      for (int r = 0; r < 4; ++r) {
        const int row = bm + wr * 64 + m * 16 + hi * 4 + r;
        const int col = bn + wc * 64 + n * 16 + lo;
        const size_t idx = (size_t)row * ldc + col;
        if constexpr (EPI == 0)      Cf[idx] = acc[m][n][r];
        else if constexpr (EPI == 1) Cf[idx] += acc[m][n][r];
        else                         Cb[idx] = f2bf(acc[m][n][r]);
      }
}

// ---------------- 256^2 bf16 GEMM, ring-3 K32 tiles, m201-style 2-phase K-step ----------------
#define G_SLOT  16384
#define G_STRIDE 32768
#define G_LDS   98304

__global__ __launch_bounds__(512, 2) void k_gemm256(
    const unsigned short* __restrict__ A, int lda,
    const unsigned short* __restrict__ Bt, int ldb,
    float* __restrict__ C, int M, int N, int K) {
  extern __shared__ char lds[];
  const int t = threadIdx.x;
  const int lane = t & 63;
  const int wid = t >> 6;
  const int wr = wid >> 2;
  const int wc = wid & 3;
  const int lo = lane & 15, hi = lane >> 4;

  const int nwg = gridDim.x;
  const int chunk = nwg >> 3;
  const int remap = ((int)blockIdx.x & 7) * chunk + ((int)blockIdx.x >> 3);
  const int nx = N >> 8;
  const int bm = (remap / nx) << 8;
  const int bn = (remap % nx) << 8;

  const int NT = K >> 5;

  const int c0 = t,       r0 = c0 >> 2, s0 = (c0 & 3) ^ ((r0 >> 1) & 3);
  const int c1 = t + 512, r1 = c1 >> 2, s1 = (c1 & 3) ^ ((r1 >> 1) & 3);
  const unsigned short* Ap0 = A  + (size_t)(bm + r0) * lda + s0 * 8;
  const unsigned short* Ap1 = A  + (size_t)(bm + r1) * lda + s1 * 8;
  const unsigned short* Bp0 = Bt + (size_t)(bn + r0) * ldb + s0 * 8;
  const unsigned short* Bp1 = Bt + (size_t)(bn + r1) * ldb + s1 * 8;

  const int ksl = ((hi ^ ((lo >> 1) & 3)) << 4);
  const int aBase = wr * 8192 + lo * 64 + ksl;            // + m*1024
  const int bBase = G_SLOT + wc * 4096 + lo * 64 + ksl;   // + n*1024

  f32x4 acc[8][4] = {};

#define STAGE_A(tt_) do {                                          \
    char* _b = lds + ((tt_) % 3) * G_STRIDE;                       \
    const int _kt = (tt_) << 5;                                    \
    lds_load16(Ap0 + _kt, _b + c0 * 16);                           \
    lds_load16(Ap1 + _kt, _b + c1 * 16);                           \
  } while (0)
#define STAGE_B(tt_) do {                                          \
    char* _b = lds + ((tt_) % 3) * G_STRIDE;                       \
    const int _kt = (tt_) << 5;                                    \
    lds_load16(Bp0 + _kt, _b + G_SLOT + c0 * 16);                  \
    lds_load16(Bp1 + _kt, _b + G_SLOT + c1 * 16);                  \
  } while (0)

  STAGE_A(0); STAGE_B(0);
  STAGE_A(1); STAGE_B(1);
  asm volatile("s_waitcnt vmcnt(4)" ::: "memory");
  __builtin_amdgcn_sched_barrier(0);
  __builtin_amdgcn_s_barrier();

  for (int tt = 0; tt < NT; ++tt) {
    const char* sa = lds + (tt % 3) * G_STRIDE;
    bf16x8 a[8], b[4];

    // ---------------- phase A ----------------
#pragma unroll
    for (int n = 0; n < 4; ++n) b[n] = *(const bf16x8*)(sa + bBase + n * 1024);
#pragma unroll
    for (int m = 0; m < 4; ++m) a[m] = *(const bf16x8*)(sa + aBase + m * 1024);
    if (tt + 2 < NT) STAGE_A(tt + 2);
    __builtin_amdgcn_s_barrier();                 // pre-MFMA
    asm volatile("s_waitcnt lgkmcnt(0)" ::: "memory");
    __builtin_amdgcn_sched_barrier(0);
    __builtin_amdgcn_s_setprio(1);
#pragma unroll
    for (int m = 0; m < 4; ++m)
#pragma unroll
      for (int n = 0; n < 4; ++n)
        acc[m][n] = __builtin_amdgcn_mfma_f32_16x16x32_bf16(a[m], b[n], acc[m][n], 0, 0, 0);
    __builtin_amdgcn_s_setprio(0);
    __builtin_amdgcn_s_barrier();                 // post-MFMA

    // ---------------- phase B ----------------
#pragma unroll
    for (int m = 4; m < 8; ++m) a[m] = *(const bf16x8*)(sa + aBase + m * 1024);
    if (tt + 2 < NT) {
      STAGE_B(tt + 2);
      asm volatile("s_waitcnt vmcnt(4)" ::: "memory");   // tile tt+1 landed; tt+2 in flight
    } else if (tt + 1 < NT) {
      asm volatile("s_waitcnt vmcnt(0)" ::: "memory");   // epilogue drain
    }
    __builtin_amdgcn_s_barrier();                 // pre-MFMA (publishes vmcnt)
    asm volatile("s_waitcnt lgkmcnt(0)" ::: "memory");
    __builtin_amdgcn_sched_barrier(0);
    __builtin_amdgcn_s_setprio(1);
#pragma unroll
    for (int m = 4; m < 8; ++m)
#pragma unroll
      for (int n = 0; n < 4; ++n)
        acc[m][n] = __builtin_amdgcn_mfma_f32_16x16x32_bf16(a[m], b[n], acc[m][n], 0, 0, 0);
    __builtin_amdgcn_s_setprio(0);
    __builtin_amdgcn_s_barrier();                 // post-MFMA / tile boundary
  }
#undef STAGE_A
#undef STAGE_B

#pragma unroll
  for (int m = 0; m < 8; ++m)
#pragma unroll
    for (int n = 0; n < 4; ++n)
#pragma unroll
      for (int r = 0; r < 4; ++r) {
        const int row = bm + wr * 128 + m * 16 + hi * 4 + r;
        const int col = bn + wc * 64 + n * 16 + lo;
        C[(size_t)row * N + col] = acc[m][n][r];
      }
}

extern "C" void kernel_launch(void* const* d_in, const int* in_sizes, int n_in,
                              void* d_out, int out_size, void* d_ws, size_t ws_size,
                              hipStream_t stream) {
  const float* x   = (const float*)d_in[0];
  const float* sel = (const float*)d_in[1];
  const float* ew  = (const float*)d_in[2];   // [4096 k][4096 o]
  const float* wc1 = (const float*)d_in[3];   // [4096][512]
  const float* wc2 = (const float*)d_in[4];   // [512][4096]
  float* out = (float*)d_out;

  char* ws = (char*)d_ws;
  unsigned short* xcat  = (unsigned short*)(ws);
  unsigned short* xm    = (unsigned short*)(ws + 75497472);
  unsigned short* btcat = (unsigned short*)(ws + 75497472);
  unsigned short* w1ct  = (unsigned short*)(ws + 142606336);

  (void)hipFuncSetAttribute((const void*)k_gemm256,
                            hipFuncAttributeMaxDynamicSharedMemorySize, G_LDS);

  k_route<<<BATCH, 256, 0, stream>>>(x, sel, xcat, xm);
  k_transpose_bf16<<<dim3(COMP / 64, IN_F / 64), 256, 0, stream>>>(wc1, w1ct, IN_F, COMP, IN_F);
  k_gemm_bt<2><<<dim3(COMP / BN, BATCH / BM), 256, 0, stream>>>(
      xm, IN_F, w1ct, IN_F, (void*)(xcat + IN_F), KCAT, BATCH, COMP, IN_F);
  k_transpose_bf16<<<dim3(OUT_F / 64, IN_F / 64), 256, 0, stream>>>(ew, btcat, IN_F, OUT_F, KCAT);
  k_transpose_bf16<<<dim3(OUT_F / 64, COMP / 64), 256, 0, stream>>>(wc2, btcat + IN_F, COMP, OUT_F, KCAT);
  k_gemm256<<<(BATCH / 256) * (OUT_F / 256), 512, G_LDS, stream>>>(
      xcat, KCAT, btcat, KCAT, out, BATCH, OUT_F, KCAT);
}